// Round 2
// baseline (1353.533 us; speedup 1.0000x reference)
//
#include <hip/hip_runtime.h>
#include <math.h>

#define N_STUDENT 100000
#define N_ITEM    20000
#define N_EDGES   1000000
#define IN_CH     128
#define EDGE_DIM  32
#define DEC_CH    64

// Thread-per-row GEMM: out[r][:] = act(X[r][:] @ W (+ b))
// X rows: per-lane float4 vector loads (64B/chunk per thread = whole cache
// lines, dense across the wave). W/b: wave-uniform indices -> compiler emits
// s_load; SGPR operand feeds v_fmac directly (no LDS, no extra VALU).
// MODE 0: identity, no bias. MODE 1: softplus with bias.
template<int MODE>
__global__ __launch_bounds__(256) void rowgemm_kernel(
    const float* __restrict__ X, const float* __restrict__ W,
    const float* __restrict__ b, float* __restrict__ out, int nrows)
{
    const int r = blockIdx.x * blockDim.x + threadIdx.x;
    if (r >= nrows) return;

    float acc[DEC_CH];
    #pragma unroll
    for (int c = 0; c < DEC_CH; ++c) acc[c] = (MODE == 1) ? b[c] : 0.f;

    const float4* xr = (const float4*)(X + (size_t)r * IN_CH);

    for (int kk = 0; kk < IN_CH; kk += 16) {   // 64B of x per chunk
        float4 v0 = xr[kk / 4 + 0];
        float4 v1 = xr[kk / 4 + 1];
        float4 v2 = xr[kk / 4 + 2];
        float4 v3 = xr[kk / 4 + 3];
        float xs[16] = {v0.x, v0.y, v0.z, v0.w, v1.x, v1.y, v1.z, v1.w,
                        v2.x, v2.y, v2.z, v2.w, v3.x, v3.y, v3.z, v3.w};
        #pragma unroll
        for (int j = 0; j < 16; ++j) {
            const float* wrow = W + (kk + j) * DEC_CH;   // uniform -> s_load
            #pragma unroll
            for (int c = 0; c < DEC_CH; ++c)
                acc[c] = fmaf(xs[j], wrow[c], acc[c]);
        }
    }

    float4* o = (float4*)(out + (size_t)r * DEC_CH);
    #pragma unroll
    for (int q = 0; q < DEC_CH / 4; ++q) {
        float4 v;
        if (MODE == 1) {
            // softplus(x) = max(x,0) + log1p(exp(-|x|))
            v.x = fmaxf(acc[4*q+0], 0.f) + log1pf(expf(-fabsf(acc[4*q+0])));
            v.y = fmaxf(acc[4*q+1], 0.f) + log1pf(expf(-fabsf(acc[4*q+1])));
            v.z = fmaxf(acc[4*q+2], 0.f) + log1pf(expf(-fabsf(acc[4*q+2])));
            v.w = fmaxf(acc[4*q+3], 0.f) + log1pf(expf(-fabsf(acc[4*q+3])));
        } else {
            v.x = acc[4*q+0]; v.y = acc[4*q+1]; v.z = acc[4*q+2]; v.w = acc[4*q+3];
        }
        o[q] = v;
    }
}

// Thread-per-edge: coalesced idx/edge_feat/out, float4 row gathers from the
// precomputed tables (hot set ~10MB -> L2/L3), W1[128:160] + b1 via SGPRs.
__global__ __launch_bounds__(256) void edge_kernel(
    const int* __restrict__ idx, const float* __restrict__ ef,
    const float* __restrict__ W1, const float* __restrict__ b1,
    const float* __restrict__ offset, const float* __restrict__ s_part,
    const float* __restrict__ y_item, float* __restrict__ out)
{
    const int e = blockIdx.x * blockDim.x + threadIdx.x;
    if (e >= N_EDGES) return;

    const int is = idx[e];
    const int ii = idx[N_EDGES + e];

    // acc = s_part[is][:] + b1
    float acc[DEC_CH];
    {
        const float4* sp = (const float4*)(s_part + (size_t)is * DEC_CH);
        #pragma unroll
        for (int q = 0; q < DEC_CH / 4; ++q) {
            float4 v = sp[q];
            acc[4*q+0] = v.x + b1[4*q+0];
            acc[4*q+1] = v.y + b1[4*q+1];
            acc[4*q+2] = v.z + b1[4*q+2];
            acc[4*q+3] = v.w + b1[4*q+3];
        }
    }

    // acc += edge_feat[e][:] @ W1[128:160][:]
    const float* Wb = W1 + IN_CH * DEC_CH;
    const float4* efr = (const float4*)(ef + (size_t)e * EDGE_DIM);
    #pragma unroll
    for (int kk = 0; kk < EDGE_DIM; kk += 8) {
        float4 e0 = efr[kk / 4 + 0];
        float4 e1 = efr[kk / 4 + 1];
        float es[8] = {e0.x, e0.y, e0.z, e0.w, e1.x, e1.y, e1.z, e1.w};
        #pragma unroll
        for (int j = 0; j < 8; ++j) {
            const float* wrow = Wb + (kk + j) * DEC_CH;   // uniform -> s_load
            #pragma unroll
            for (int c = 0; c < DEC_CH; ++c)
                acc[c] = fmaf(es[j], wrow[c], acc[c]);
        }
    }

    // out[e] = sum_c elu(acc[c]) * y_item[ii][c] + offset[ii]
    const float4* yp = (const float4*)(y_item + (size_t)ii * DEC_CH);
    float p0 = 0.f, p1 = 0.f, p2 = 0.f, p3 = 0.f;
    #pragma unroll
    for (int q = 0; q < DEC_CH / 4; ++q) {
        float4 yv = yp[q];
        float x0 = acc[4*q+0] > 0.f ? acc[4*q+0] : expm1f(acc[4*q+0]);
        float x1 = acc[4*q+1] > 0.f ? acc[4*q+1] : expm1f(acc[4*q+1]);
        float x2 = acc[4*q+2] > 0.f ? acc[4*q+2] : expm1f(acc[4*q+2]);
        float x3 = acc[4*q+3] > 0.f ? acc[4*q+3] : expm1f(acc[4*q+3]);
        p0 = fmaf(x0, yv.x, p0);
        p1 = fmaf(x1, yv.y, p1);
        p2 = fmaf(x2, yv.z, p2);
        p3 = fmaf(x3, yv.w, p3);
    }
    out[e] = (p0 + p1) + (p2 + p3) + offset[ii];
}

extern "C" void kernel_launch(void* const* d_in, const int* in_sizes, int n_in,
                              void* d_out, int out_size, void* d_ws, size_t ws_size,
                              hipStream_t stream) {
    const float* x_student = (const float*)d_in[0];
    const float* x_item    = (const float*)d_in[1];
    const int*   eli       = (const int*)d_in[2];
    const float* edge_feat = (const float*)d_in[3];
    const float* offset    = (const float*)d_in[4];
    const float* W1        = (const float*)d_in[5];
    const float* b1        = (const float*)d_in[6];
    const float* W2        = (const float*)d_in[7];
    const float* b2        = (const float*)d_in[8];
    float* out = (float*)d_out;

    float* s_part = (float*)d_ws;                            // 100000*64 f32 = 25.6 MB
    float* y_item = s_part + (size_t)N_STUDENT * DEC_CH;     // 20000*64  f32 =  5.1 MB

    rowgemm_kernel<0><<<(N_STUDENT + 255) / 256, 256, 0, stream>>>(
        x_student, W1, nullptr, s_part, N_STUDENT);
    rowgemm_kernel<1><<<(N_ITEM + 255) / 256, 256, 0, stream>>>(
        x_item, W2, b2, y_item, N_ITEM);
    edge_kernel<<<(N_EDGES + 255) / 256, 256, 0, stream>>>(
        eli, edge_feat, W1, b1, offset, s_part, y_item, out);
}

// Round 3
// 565.788 us; speedup vs baseline: 2.3923x; 2.3923x over previous
//
#include <hip/hip_runtime.h>
#include <math.h>

#define N_STUDENT 100000
#define N_ITEM    20000
#define N_EDGES   1000000
#define IN_CH     128
#define EDGE_DIM  32
#define DEC_CH    64

// ---------------------------------------------------------------------------
// rowgemm: out[r][lane] = act( X[r][:] @ W[:,lane] (+ b[lane]) )
// - 64-row tile staged to LDS with coalesced per-lane float4 loads
// - W column W[k][lane] held in 128 VGPRs (one accumulator per thread!)
// - X row values read back as wave-uniform ds_read_b128 broadcasts
// MODE 0: identity, no bias (student path). MODE 1: softplus + bias (item).
// ---------------------------------------------------------------------------
template<int MODE>
__global__ __launch_bounds__(256) void rowgemm_kernel(
    const float* __restrict__ X, const float* __restrict__ W,
    const float* __restrict__ b, float* __restrict__ out, int nrows)
{
    __shared__ float sX[64 * IN_CH];            // 32 KB

    const int lane = threadIdx.x & 63;
    const int wib  = threadIdx.x >> 6;

    // per-lane weight column, loaded coalesced (256B per wave-inst)
    float Wr[IN_CH];
    #pragma unroll
    for (int k = 0; k < IN_CH; ++k) Wr[k] = W[k * DEC_CH + lane];
    const float bv = (MODE == 1) ? b[lane] : 0.f;

    const int r0 = blockIdx.x * 64;
    const int nt = min(64, nrows - r0);         // rows in this tile

    // stage tile: nt*128 floats, coalesced float4
    {
        const float4* src = (const float4*)(X + (size_t)r0 * IN_CH);
        float4* dst = (float4*)sX;
        const int lim = nt * (IN_CH / 4);
        #pragma unroll
        for (int p = 0; p < 8; ++p) {
            int i = p * 256 + threadIdx.x;
            if (i < lim) dst[i] = src[i];
        }
    }
    __syncthreads();

    // wave handles rows [wib*16, wib*16+16)
    for (int j = 0; j < 16; ++j) {
        const int lr = wib * 16 + j;
        if (lr >= nt) break;
        const float4* xr = (const float4*)(sX + lr * IN_CH);
        float acc = bv;
        #pragma unroll
        for (int q = 0; q < IN_CH / 4; ++q) {
            float4 xv = xr[q];                  // uniform addr -> broadcast
            acc = fmaf(xv.x, Wr[4*q+0], acc);
            acc = fmaf(xv.y, Wr[4*q+1], acc);
            acc = fmaf(xv.z, Wr[4*q+2], acc);
            acc = fmaf(xv.w, Wr[4*q+3], acc);
        }
        if (MODE == 1)   // softplus(x) = max(x,0) + log1p(exp(-|x|))
            acc = fmaxf(acc, 0.f) + log1pf(expf(-fabsf(acc)));
        out[(size_t)(r0 + lr) * DEC_CH + lane] = acc;
    }
}

// ---------------------------------------------------------------------------
// edge kernel: per edge e with (is, ii):
//   acc[c] = s_part[is][c] + b1[c] + ef[e][:] @ W1b[:,c]
//   out[e] = sum_c elu(acc[c]) * y_item[ii][c] + offset[ii]
// lane = channel c; 256-edge tile staged in LDS; W1b column in 32 VGPRs.
// ---------------------------------------------------------------------------
__global__ __launch_bounds__(256) void edge_kernel(
    const int* __restrict__ idx, const float* __restrict__ ef,
    const float* __restrict__ W1, const float* __restrict__ b1,
    const float* __restrict__ offset, const float* __restrict__ s_part,
    const float* __restrict__ y_item, float* __restrict__ out)
{
    __shared__ float sEF[256 * EDGE_DIM];   // 32 KB
    __shared__ int   sIdx[2 * 256];         // (is, ii) pairs
    __shared__ float sOff[256];

    const int lane = threadIdx.x & 63;
    const int wib  = threadIdx.x >> 6;

    const float* Wb = W1 + IN_CH * DEC_CH;  // rows 128..159 of W1
    float Wr[EDGE_DIM];
    #pragma unroll
    for (int k = 0; k < EDGE_DIM; ++k) Wr[k] = Wb[k * DEC_CH + lane];
    const float bv = b1[lane];

    const int e0 = blockIdx.x * 256;
    const int nt = min(256, N_EDGES - e0);

    // stage ef tile coalesced: nt*32 floats
    {
        const float4* src = (const float4*)(ef + (size_t)e0 * EDGE_DIM);
        float4* dst = (float4*)sEF;
        const int lim = nt * (EDGE_DIM / 4);
        #pragma unroll
        for (int p = 0; p < 8; ++p) {
            int i = p * 256 + threadIdx.x;
            if (i < lim) dst[i] = src[i];
        }
    }
    // stage indices + offset gather
    if (threadIdx.x < nt) {
        const int is = idx[e0 + threadIdx.x];
        const int ii = idx[N_EDGES + e0 + threadIdx.x];
        sIdx[2 * threadIdx.x]     = is;
        sIdx[2 * threadIdx.x + 1] = ii;
        sOff[threadIdx.x] = offset[ii];
    }
    __syncthreads();

    const int lb  = wib * 64;
    const int ntw = min(64, nt - lb);       // may be <= 0 on the tail tile
    float res = 0.f;
    for (int j = 0; j < ntw; ++j) {
        const int le = lb + j;
        const int is = sIdx[2 * le];        // broadcast reads
        const int ii = sIdx[2 * le + 1];
        const float sv = s_part[(size_t)is * DEC_CH + lane];  // 256B coalesced
        const float yv = y_item[(size_t)ii * DEC_CH + lane];

        float acc = sv + bv;
        const float4* efl = (const float4*)(sEF + le * EDGE_DIM);
        #pragma unroll
        for (int q = 0; q < EDGE_DIM / 4; ++q) {
            float4 ev = efl[q];             // uniform addr -> broadcast
            acc = fmaf(ev.x, Wr[4*q+0], acc);
            acc = fmaf(ev.y, Wr[4*q+1], acc);
            acc = fmaf(ev.z, Wr[4*q+2], acc);
            acc = fmaf(ev.w, Wr[4*q+3], acc);
        }
        const float x = acc > 0.f ? acc : expm1f(acc);   // ELU(alpha=1)
        float p = x * yv;
        #pragma unroll
        for (int off = 32; off >= 1; off >>= 1)          // full butterfly
            p += __shfl_xor(p, off, 64);
        res = (lane == j) ? (p + sOff[le]) : res;
    }
    if (lane < ntw) out[e0 + lb + lane] = res;           // coalesced 256B
}

extern "C" void kernel_launch(void* const* d_in, const int* in_sizes, int n_in,
                              void* d_out, int out_size, void* d_ws, size_t ws_size,
                              hipStream_t stream) {
    const float* x_student = (const float*)d_in[0];
    const float* x_item    = (const float*)d_in[1];
    const int*   eli       = (const int*)d_in[2];
    const float* edge_feat = (const float*)d_in[3];
    const float* offset    = (const float*)d_in[4];
    const float* W1        = (const float*)d_in[5];
    const float* b1        = (const float*)d_in[6];
    const float* W2        = (const float*)d_in[7];
    const float* b2        = (const float*)d_in[8];
    float* out = (float*)d_out;

    float* s_part = (float*)d_ws;                            // 25.6 MB
    float* y_item = s_part + (size_t)N_STUDENT * DEC_CH;     //  5.1 MB

    rowgemm_kernel<0><<<(N_STUDENT + 63) / 64, 256, 0, stream>>>(
        x_student, W1, nullptr, s_part, N_STUDENT);
    rowgemm_kernel<1><<<(N_ITEM + 63) / 64, 256, 0, stream>>>(
        x_item, W2, b2, y_item, N_ITEM);
    edge_kernel<<<(N_EDGES + 255) / 256, 256, 0, stream>>>(
        eli, edge_feat, W1, b1, offset, s_part, y_item, out);
}